// Round 2
// baseline (1611.124 us; speedup 1.0000x reference)
//
#include <hip/hip_runtime.h>
#include <hip/hip_bf16.h>
#include <hip/hip_fp16.h>

// APPNP: h0 = MLP(x); 10x { h = 0.9 * A_hat h + 0.1 * h0 }; log_softmax.
// A_hat = D^-1/2 (A + I) D^-1/2 over col-targets (PyG gcn_norm).
//
// R5 post-mortem: gather was ~84us/iter = L3-bound (12.8MB h working set >
// 4MB per-XCD L2 -> ~5TB/s effective on 410MB/iter of gathered rows).
// R6: channel-split propagation. h stored plane-major [4][N][16] bf16; each
// gather pass touches one contiguous 3.2MB plane -> L2-resident per XCD
// (~34.5TB/s). Edge stream packed to 4B/edge (src<<15 | fp16norm sans sign)
// since it is re-read 4x/iter; nt loads/stores keep streams from evicting
// the plane. mlp_k: prefetch all 16 A-frags (was 16 dependent load->MFMA
// rounds at 40 VGPR = latency-bound, 840GB/s).
// R6b: nontemporal builtins need plain ext_vector types, not HIP uint4.

typedef unsigned short u16;
typedef __attribute__((ext_vector_type(8))) short short8;
typedef __attribute__((ext_vector_type(4))) float f32x4;
typedef __attribute__((ext_vector_type(4))) unsigned u32x4;

#define WPB 4        // waves (nodes) per 256-thread block in lsm
#define BSH2 9       // 512 nodes per bucket
#define BN2 512
#define NBMAX 200
#define CAP 20480    // slots per bucket region (mean 16.3k, +32 sigma)
#define SCWG 392     // scatter WGs (chunk ~8.2k edges)

// ---- helpers -------------------------------------------------------------
__device__ __forceinline__ float loadF(const void* p, size_t i, int bf) {
  if (bf) return __bfloat162float(((const __hip_bfloat16*)p)[i]);
  return ((const float*)p)[i];
}
__device__ __forceinline__ float blo(unsigned u) {
  return __uint_as_float(u << 16);
}
__device__ __forceinline__ float bhi(unsigned u) {
  return __uint_as_float(u & 0xffff0000u);
}
__device__ __forceinline__ u16 f2b(float v) {
  __hip_bfloat16 b = __float2bfloat16(v);
  return *reinterpret_cast<u16*>(&b);
}
__device__ __forceinline__ unsigned pk2(float lo, float hi) {
  return (unsigned)f2b(lo) | ((unsigned)f2b(hi) << 16);
}
__device__ __forceinline__ int clampN(int v, int N) {
  v = v < 0 ? 0 : v;
  return v >= N ? N - 1 : v;
}

// flags[0]: 1 if float tensors bf16; flags[1]: 1 if edge_index int64.
__global__ void detect_k(const void* x, const int* ei, int* flags) {
  __shared__ int red[2];
  const int tid = threadIdx.x;              // 1024 threads
  if (tid < 2) red[tid] = 0;
  __syncthreads();
  const __hip_bfloat16* xb = (const __hip_bfloat16*)x;
  float v = __bfloat162float(xb[tid]);
  int sane = (v == v && fabsf(v) < 64.f) ? 1 : 0;
  int zer = (ei[2 * tid + 1] == 0) ? 1 : 0;
  atomicAdd(&red[0], sane);
  atomicAdd(&red[1], zer);
  __syncthreads();
  if (tid == 0) {
    flags[0] = (red[0] >= 1024 - 32) ? 1 : 0;
    flags[1] = (red[1] >= 1024 - 128) ? 1 : 0;
  }
}

// Two-pass chunked scatter: per WG, (A) LDS-histogram chunk over buckets,
// (B) reserve one contiguous range per bucket, (C) re-read chunk and write
// (src,dst) into the WG-owned run -> full-line writes from one CU.
__global__ __launch_bounds__(256) void scat_k(
    const int* __restrict__ ei, int E, int N, int NB,
    int* __restrict__ gcur, uint2* __restrict__ bpair,
    const int* __restrict__ flags) {
  __shared__ int hist[NBMAX];
  __shared__ int resv[NBMAX];
  const int tid = threadIdx.x;
  const int chunk = (E + SCWG - 1) / SCWG;
  const int e0 = blockIdx.x * chunk;
  const int e1 = min(e0 + chunk, E);
  if (e0 >= E) return;
  const int wide = flags[1];
  for (int i = tid; i < NB; i += 256) hist[i] = 0;
  __syncthreads();
  for (int e = e0 + tid; e < e1; e += 256) {
    int c = wide ? ei[2 * ((long)E + e)] : ei[(long)E + e];
    atomicAdd(&hist[clampN(c, N) >> BSH2], 1);
  }
  __syncthreads();
  for (int b = tid; b < NB; b += 256) {
    int cnt = hist[b];
    resv[b] = cnt ? atomicAdd(&gcur[b], cnt) : 0;
  }
  __syncthreads();
  for (int i = tid; i < NB; i += 256) hist[i] = 0;
  __syncthreads();
  for (int e = e0 + tid; e < e1; e += 256) {
    int r = wide ? ei[2 * (long)e] : ei[e];
    int c = wide ? ei[2 * ((long)E + e)] : ei[(long)E + e];
    r = clampN(r, N); c = clampN(c, N);
    const int b = c >> BSH2;
    const int pos = resv[b] + atomicAdd(&hist[b], 1);
    if (pos < CAP)
      bpair[(size_t)b * CAP + pos] = make_uint2((unsigned)r, (unsigned)c);
  }
}

// Tiny serial scan over bucket totals -> CSR bucket bases.
__global__ void bscan_k(const int* __restrict__ gcur, int NB,
                        int* __restrict__ cbase) {
  if (threadIdx.x == 0) {
    int s = 0;
    for (int b = 0; b < NB; b++) {
      cbase[b] = s;
      s += min(gcur[b], CAP);
    }
    cbase[NB] = s;
  }
}

// Per bucket: LDS histogram over its 512 nodes + LDS scan -> colptr, dinv.
__global__ __launch_bounds__(1024) void fill2a_k(
    const uint2* __restrict__ bpair, const int* __restrict__ gcur,
    const int* __restrict__ cbase, int* __restrict__ colptr,
    float* __restrict__ dinv, int N, int NB) {
  __shared__ int lhist[BN2];
  __shared__ int pref[BN2];
  const int b = blockIdx.x;
  const int tid = threadIdx.x;
  const int nb0 = b << BSH2;
  const int nn = min(BN2, N - nb0);
  if (tid < BN2) lhist[tid] = 0;
  __syncthreads();
  const size_t wbeg = (size_t)b * CAP;
  const int cnt = min(gcur[b], CAP);
  for (int i = tid; i < cnt; i += 1024) {
    int dl = (int)bpair[wbeg + i].y - nb0;
    atomicAdd(&lhist[dl], 1);
  }
  __syncthreads();
  if (tid < BN2) pref[tid] = lhist[tid];
  __syncthreads();
  for (int off = 1; off < BN2; off <<= 1) {
    int v = 0;
    if (tid < BN2 && tid >= off) v = pref[tid - off];
    __syncthreads();
    if (tid < BN2) pref[tid] += v;
    __syncthreads();
  }
  if (tid < nn) {
    const int excl = pref[tid] - lhist[tid];
    colptr[nb0 + tid] = cbase[b] + excl;
    dinv[nb0 + tid] = rsqrtf(1.0f + (float)lhist[tid]);
  }
  if (b == NB - 1 && tid == 0) colptr[N] = cbase[NB];
}

// Per bucket: scatter edges to exact CSR slots, packing src<<15 | fp16(norm).
// norm = dinv[r]*dinv[c] in [~0.015, 0.5] -> always fp16-normal, sign 0,
// so the 15 low bits of the fp16 encode it exactly; src < 131072 fits 17b.
__global__ __launch_bounds__(1024) void fill2b_k(
    const uint2* __restrict__ bpair, const int* __restrict__ gcur,
    const int* __restrict__ colptr, const float* __restrict__ dinv,
    unsigned* __restrict__ epk, int N, int NB) {
  __shared__ int lcur[BN2];
  __shared__ float ldv[BN2];
  const int b = blockIdx.x;
  const int tid = threadIdx.x;
  const int nb0 = b << BSH2;
  const int nn = min(BN2, N - nb0);
  if (tid < nn) {
    lcur[tid] = colptr[nb0 + tid];
    ldv[tid] = dinv[nb0 + tid];
  }
  __syncthreads();
  const size_t wbeg = (size_t)b * CAP;
  const int cnt = min(gcur[b], CAP);
  for (int i = tid; i < cnt; i += 1024) {
    const uint2 p = bpair[wbeg + i];
    const int dl = (int)p.y - nb0;
    const int slot = atomicAdd(&lcur[dl], 1);
    const float nrm = dinv[p.x] * ldv[dl];
    epk[slot] = (p.x << 15) | (unsigned)__half_as_ushort(__float2half(nrm));
  }
}

// MLP via MFMA: one wave per 16-node tile (layout verified in R3).
// h0/ping written plane-major: [plane=c>>4][node][c&15] bf16.
__global__ __launch_bounds__(256) void mlp_k(
    const void* __restrict__ x, const void* __restrict__ W1,
    const void* __restrict__ b1, const void* __restrict__ W2,
    const void* __restrict__ b2, const int* __restrict__ flags,
    u16* __restrict__ h0, u16* __restrict__ ping, int N) {
  __shared__ __align__(16) short Blds[8192];   // [kstep][lane][j] bf16
  __shared__ float W2s[16 * 64];
  __shared__ float b1s[16];
  __shared__ float b2s[64];
  __shared__ float h1s[WPB][16][17];

  const int tid = threadIdx.x;
  const int f0 = flags[0];

  for (int idx = tid; idx < 8192; idx += 256) {
    int ks = idx >> 9, ln = (idx >> 3) & 63, j = idx & 7;
    int k = ks * 32 + ((ln >> 4) << 3) + j;
    int n = ln & 15;
    float w = loadF(W1, (size_t)k * 16 + n, f0);
    Blds[idx] = (short)f2b(w);
  }
  for (int idx = tid; idx < 1024; idx += 256) W2s[idx] = loadF(W2, idx, f0);
  if (tid < 16) b1s[tid] = loadF(b1, tid, f0);
  else if (tid >= 64 && tid < 128) b2s[tid - 64] = loadF(b2, tid - 64, f0);
  __syncthreads();

  const int lane = tid & 63;
  const int wv = tid >> 6;
  const int tile = (blockIdx.x * WPB + wv) * 16;
  if (tile >= N) return;

  const int m = lane & 15;
  const int quad = lane >> 4;
  const int row = min(tile + m, N - 1);
  const size_t rowbase = (size_t)row * 512 + (quad << 3);

  f32x4 acc = {0.f, 0.f, 0.f, 0.f};
  if (f0) {
    // Prefetch all 16 A-frags: 16 independent 16B loads in flight (was a
    // dependent load->MFMA chain; 40 VGPR -> ~110, still 4 waves/SIMD).
    short8 af[16];
#pragma unroll
    for (int ks = 0; ks < 16; ks++)
      af[ks] = *reinterpret_cast<const short8*>((const u16*)x + rowbase + ks * 32);
#pragma unroll
    for (int ks = 0; ks < 16; ks++) {
      const short8 bf = *reinterpret_cast<const short8*>(&Blds[(ks * 64 + lane) * 8]);
      acc = __builtin_amdgcn_mfma_f32_16x16x32_bf16(af[ks], bf, acc, 0, 0, 0);
    }
  } else {
#pragma unroll
    for (int ks = 0; ks < 16; ks++) {
      short8 a;
      const float* xf = (const float*)x + rowbase + ks * 32;
      const float4 lo = *reinterpret_cast<const float4*>(xf);
      const float4 hi = *reinterpret_cast<const float4*>(xf + 4);
      a[0] = (short)f2b(lo.x); a[1] = (short)f2b(lo.y);
      a[2] = (short)f2b(lo.z); a[3] = (short)f2b(lo.w);
      a[4] = (short)f2b(hi.x); a[5] = (short)f2b(hi.y);
      a[6] = (short)f2b(hi.z); a[7] = (short)f2b(hi.w);
      const short8 bf = *reinterpret_cast<const short8*>(&Blds[(ks * 64 + lane) * 8]);
      acc = __builtin_amdgcn_mfma_f32_16x16x32_bf16(a, bf, acc, 0, 0, 0);
    }
  }

#pragma unroll
  for (int r = 0; r < 4; r++)
    h1s[wv][quad * 4 + r][m] = fmaxf(acc[r] + b1s[m], 0.f);

  for (int mm = 0; mm < 16; mm++) {
    const int node = tile + mm;
    if (node >= N) break;
    float hh = b2s[lane];
#pragma unroll
    for (int j = 0; j < 16; j++) hh += h1s[wv][mm][j] * W2s[(j << 6) + lane];
    const u16 u = f2b(hh);
    const size_t o = ((size_t)(lane >> 4) * N + node) * 16 + (lane & 15);
    h0[o] = u;
    ping[o] = u;
  }
}

// Channel-split gather: gridDim.y = plane (16 channels, 3.2MB contiguous ->
// L2-resident per XCD). Wave = 4 targets x 8 edge-slots x 2 half-row lanes.
// Per edge: 4B packed stream read (nt) + 16B L2-hit row slice + 8 FMA.
__global__ __launch_bounds__(256) void gather_k(
    const u16* __restrict__ hcur, const u16* __restrict__ h0,
    const int* __restrict__ colptr, const unsigned* __restrict__ epk,
    const float* __restrict__ dinv, u16* __restrict__ hnext, int N) {
  const int p = blockIdx.y;                     // channel plane 0..3
  const int lane = threadIdx.x & 63;
  const int wv = threadIdx.x >> 6;
  const int grp = lane >> 4;                    // target within wave
  const int l16 = lane & 15;
  const int es = l16 >> 1;                      // edge slot 0..7
  const int ho = (l16 & 1) << 3;                // 8-channel half offset
  const int gw = blockIdx.x * 16 + wv * 4 + grp;
  if (gw >= N) return;
  const u16* __restrict__ hp = hcur + (((size_t)p * N) << 4);
  const int beg = colptr[gw];
  const int end = colptr[gw + 1];

  float a0 = 0.f, a1 = 0.f, a2 = 0.f, a3 = 0.f;
  float a4 = 0.f, a5 = 0.f, a6 = 0.f, a7 = 0.f;
  int slot = beg + es;
  while (__any(slot < end)) {
    if (slot < end) {
      const unsigned e = __builtin_nontemporal_load(epk + slot);
      const float n =
          __half2float(__ushort_as_half((unsigned short)(e & 0x7fffu)));
      const u32x4 u = *reinterpret_cast<const u32x4*>(
          hp + (((size_t)(e >> 15)) << 4) + ho);
      a0 = fmaf(n, blo(u[0]), a0); a1 = fmaf(n, bhi(u[0]), a1);
      a2 = fmaf(n, blo(u[1]), a2); a3 = fmaf(n, bhi(u[1]), a3);
      a4 = fmaf(n, blo(u[2]), a4); a5 = fmaf(n, bhi(u[2]), a5);
      a6 = fmaf(n, blo(u[3]), a6); a7 = fmaf(n, bhi(u[3]), a7);
    }
    slot += 8;
  }
  // reduce across the 8 edge slots (lane bits 1..3); half/grp preserved
#pragma unroll
  for (int d = 2; d <= 8; d <<= 1) {
    a0 += __shfl_xor(a0, d, 64); a1 += __shfl_xor(a1, d, 64);
    a2 += __shfl_xor(a2, d, 64); a3 += __shfl_xor(a3, d, 64);
    a4 += __shfl_xor(a4, d, 64); a5 += __shfl_xor(a5, d, 64);
    a6 += __shfl_xor(a6, d, 64); a7 += __shfl_xor(a7, d, 64);
  }
  if (es == 0) {
    const size_t base = (((size_t)p * N + gw) << 4) + ho;
    const u32x4 hs = *reinterpret_cast<const u32x4*>(hcur + base);
    const u32x4 hz =
        __builtin_nontemporal_load(reinterpret_cast<const u32x4*>(h0 + base));
    const float di = dinv[gw];
    const float dd = di * di;
    const float r0 = 0.9f * (a0 + dd * blo(hs[0])) + 0.1f * blo(hz[0]);
    const float r1 = 0.9f * (a1 + dd * bhi(hs[0])) + 0.1f * bhi(hz[0]);
    const float r2 = 0.9f * (a2 + dd * blo(hs[1])) + 0.1f * blo(hz[1]);
    const float r3 = 0.9f * (a3 + dd * bhi(hs[1])) + 0.1f * bhi(hz[1]);
    const float r4 = 0.9f * (a4 + dd * blo(hs[2])) + 0.1f * blo(hz[2]);
    const float r5 = 0.9f * (a5 + dd * bhi(hs[2])) + 0.1f * bhi(hz[2]);
    const float r6 = 0.9f * (a6 + dd * blo(hs[3])) + 0.1f * blo(hz[3]);
    const float r7 = 0.9f * (a7 + dd * bhi(hs[3])) + 0.1f * bhi(hz[3]);
    u32x4 pv;
    pv[0] = pk2(r0, r1); pv[1] = pk2(r2, r3);
    pv[2] = pk2(r4, r5); pv[3] = pk2(r6, r7);
    __builtin_nontemporal_store(pv, reinterpret_cast<u32x4*>(hnext + base));
  }
}

__global__ __launch_bounds__(256) void lsm_k(const u16* __restrict__ hin,
                                             void* __restrict__ out,
                                             const int* __restrict__ flags, int N) {
  const int gw = (int)((blockIdx.x * 256u + threadIdx.x) >> 6);
  if (gw >= N) return;
  const int lane = threadIdx.x & 63;
  const size_t oin = ((size_t)(lane >> 4) * N + gw) * 16 + (lane & 15);
  const float v = __bfloat162float(*reinterpret_cast<const __hip_bfloat16*>(&hin[oin]));
  float m = v;
#pragma unroll
  for (int off = 32; off; off >>= 1) m = fmaxf(m, __shfl_xor(m, off, 64));
  float e = __expf(v - m);
  float ssum = e;
#pragma unroll
  for (int off = 32; off; off >>= 1) ssum += __shfl_xor(ssum, off, 64);
  const float r = v - m - __logf(ssum);
  const size_t o = (((size_t)gw) << 6) + lane;
  if (flags[0]) ((__hip_bfloat16*)out)[o] = __float2bfloat16(r);
  else ((float*)out)[o] = r;
}

extern "C" void kernel_launch(void* const* d_in, const int* in_sizes, int n_in,
                              void* d_out, int out_size, void* d_ws, size_t ws_size,
                              hipStream_t stream) {
  (void)n_in; (void)out_size; (void)ws_size;
  const void* x  = d_in[0];
  const void* W1 = d_in[1];
  const void* b1 = d_in[2];
  const void* W2 = d_in[3];
  const void* b2 = d_in[4];
  const int* ei  = (const int*)d_in[5];

  const int N = in_sizes[0] / 512;
  const int E = in_sizes[5] / 2;
  const int NB = (N + BN2 - 1) >> BSH2;    // 196 for N=100k (fits NBMAX=200)

  char* w = (char*)d_ws;
  size_t off = 0;
  auto alloc = [&](size_t bytes) -> void* {
    void* p = w + off;
    off += (bytes + 255) & ~(size_t)255;
    return p;
  };
  // Region A: bpair bucket regions (build) overlaid by h0+ping (propagate).
  const size_t hb = (size_t)N * 64 * 2;
  const size_t bpb = (size_t)NB * CAP * 8;
  char*  regionA = (char*)alloc(2 * hb > bpb ? 2 * hb : bpb);
  u16*   h0     = (u16*)regionA;
  u16*   ping   = (u16*)(regionA + hb);
  uint2* bpair  = (uint2*)regionA;
  unsigned* epk = (unsigned*)alloc((size_t)E * 4);
  int*   colptr = (int*)alloc(((size_t)N + 1) * 4);
  float* dinv   = (float*)alloc((size_t)N * 4);
  int*   gcur   = (int*)alloc((size_t)NB * 4);
  int*   cbase  = (int*)alloc(((size_t)NB + 1) * 4);
  int*   flags  = (int*)alloc(256);
  u16*   pong   = (u16*)d_out;

  hipMemsetAsync(gcur, 0, (size_t)NB * 4, stream);
  detect_k<<<1, 1024, 0, stream>>>(x, ei, flags);
  scat_k<<<SCWG, 256, 0, stream>>>(ei, E, N, NB, gcur, bpair, flags);
  bscan_k<<<1, 64, 0, stream>>>(gcur, NB, cbase);
  fill2a_k<<<NB, 1024, 0, stream>>>(bpair, gcur, cbase, colptr, dinv, N, NB);
  fill2b_k<<<NB, 1024, 0, stream>>>(bpair, gcur, colptr, dinv, epk, N, NB);
  // mlp after fill2b: h0/ping overwrite bpair (lifetime ended).
  mlp_k<<<(N + 63) / 64, 256, 0, stream>>>(x, W1, b1, W2, b2, flags, h0, ping, N);

  const int gpb = (N + 15) >> 4;           // target blocks per plane
  dim3 ggrid(gpb, 4);                      // x fastest -> plane-major order
  for (int it = 0; it < 10; ++it) {
    if ((it & 1) == 0)
      gather_k<<<ggrid, 256, 0, stream>>>(ping, h0, colptr, epk, dinv, pong, N);
    else
      gather_k<<<ggrid, 256, 0, stream>>>(pong, h0, colptr, epk, dinv, ping, N);
  }
  // it9 wrote ping
  lsm_k<<<(N + WPB - 1) / WPB, 256, 0, stream>>>(ping, d_out, flags, N);
}

// Round 3
// 1531.476 us; speedup vs baseline: 1.0520x; 1.0520x over previous
//
#include <hip/hip_runtime.h>
#include <hip/hip_bf16.h>
#include <hip/hip_fp16.h>

// APPNP: h0 = MLP(x); 10x { h = 0.9 * A_hat h + 0.1 * h0 }; log_softmax.
// A_hat = D^-1/2 (A + I) D^-1/2 over col-targets (PyG gcn_norm).
//
// R6 post-mortem: channel-split regressed (1080->1611us) because the new
// gather loop had ONE dependent load chain per iteration + a ballot (MLP
// collapsed from R0's 8 outstanding loads/lane to 1). R7: keep plane-major
// [4][N][16] layout + 4B nt edge stream (L2 stays clean for the 3.2MB
// plane), but restore R0's loop shape: unroll 4 over slot-stride 8, two
// acc banks, predicated tail, no ballots. Per-lane MLP == R0, row reads
// now L2-resident.

typedef unsigned short u16;
typedef __attribute__((ext_vector_type(8))) short short8;
typedef __attribute__((ext_vector_type(4))) float f32x4;
typedef __attribute__((ext_vector_type(4))) unsigned u32x4;

#define WPB 4        // waves (nodes) per 256-thread block in lsm
#define BSH2 9       // 512 nodes per bucket
#define BN2 512
#define NBMAX 200
#define CAP 20480    // slots per bucket region (mean 16.3k, +32 sigma)
#define SCWG 392     // scatter WGs (chunk ~8.2k edges)

// ---- helpers -------------------------------------------------------------
__device__ __forceinline__ float loadF(const void* p, size_t i, int bf) {
  if (bf) return __bfloat162float(((const __hip_bfloat16*)p)[i]);
  return ((const float*)p)[i];
}
__device__ __forceinline__ float blo(unsigned u) {
  return __uint_as_float(u << 16);
}
__device__ __forceinline__ float bhi(unsigned u) {
  return __uint_as_float(u & 0xffff0000u);
}
__device__ __forceinline__ u16 f2b(float v) {
  __hip_bfloat16 b = __float2bfloat16(v);
  return *reinterpret_cast<u16*>(&b);
}
__device__ __forceinline__ unsigned pk2(float lo, float hi) {
  return (unsigned)f2b(lo) | ((unsigned)f2b(hi) << 16);
}
__device__ __forceinline__ int clampN(int v, int N) {
  v = v < 0 ? 0 : v;
  return v >= N ? N - 1 : v;
}
__device__ __forceinline__ float nrm_of(unsigned e) {
  return __half2float(__ushort_as_half((unsigned short)(e & 0x7fffu)));
}

// flags[0]: 1 if float tensors bf16; flags[1]: 1 if edge_index int64.
__global__ void detect_k(const void* x, const int* ei, int* flags) {
  __shared__ int red[2];
  const int tid = threadIdx.x;              // 1024 threads
  if (tid < 2) red[tid] = 0;
  __syncthreads();
  const __hip_bfloat16* xb = (const __hip_bfloat16*)x;
  float v = __bfloat162float(xb[tid]);
  int sane = (v == v && fabsf(v) < 64.f) ? 1 : 0;
  int zer = (ei[2 * tid + 1] == 0) ? 1 : 0;
  atomicAdd(&red[0], sane);
  atomicAdd(&red[1], zer);
  __syncthreads();
  if (tid == 0) {
    flags[0] = (red[0] >= 1024 - 32) ? 1 : 0;
    flags[1] = (red[1] >= 1024 - 128) ? 1 : 0;
  }
}

// Two-pass chunked scatter: per WG, (A) LDS-histogram chunk over buckets,
// (B) reserve one contiguous range per bucket, (C) re-read chunk and write
// (src,dst) into the WG-owned run -> full-line writes from one CU.
__global__ __launch_bounds__(256) void scat_k(
    const int* __restrict__ ei, int E, int N, int NB,
    int* __restrict__ gcur, uint2* __restrict__ bpair,
    const int* __restrict__ flags) {
  __shared__ int hist[NBMAX];
  __shared__ int resv[NBMAX];
  const int tid = threadIdx.x;
  const int chunk = (E + SCWG - 1) / SCWG;
  const int e0 = blockIdx.x * chunk;
  const int e1 = min(e0 + chunk, E);
  if (e0 >= E) return;
  const int wide = flags[1];
  for (int i = tid; i < NB; i += 256) hist[i] = 0;
  __syncthreads();
  for (int e = e0 + tid; e < e1; e += 256) {
    int c = wide ? ei[2 * ((long)E + e)] : ei[(long)E + e];
    atomicAdd(&hist[clampN(c, N) >> BSH2], 1);
  }
  __syncthreads();
  for (int b = tid; b < NB; b += 256) {
    int cnt = hist[b];
    resv[b] = cnt ? atomicAdd(&gcur[b], cnt) : 0;
  }
  __syncthreads();
  for (int i = tid; i < NB; i += 256) hist[i] = 0;
  __syncthreads();
  for (int e = e0 + tid; e < e1; e += 256) {
    int r = wide ? ei[2 * (long)e] : ei[e];
    int c = wide ? ei[2 * ((long)E + e)] : ei[(long)E + e];
    r = clampN(r, N); c = clampN(c, N);
    const int b = c >> BSH2;
    const int pos = resv[b] + atomicAdd(&hist[b], 1);
    if (pos < CAP)
      bpair[(size_t)b * CAP + pos] = make_uint2((unsigned)r, (unsigned)c);
  }
}

// Tiny serial scan over bucket totals -> CSR bucket bases.
__global__ void bscan_k(const int* __restrict__ gcur, int NB,
                        int* __restrict__ cbase) {
  if (threadIdx.x == 0) {
    int s = 0;
    for (int b = 0; b < NB; b++) {
      cbase[b] = s;
      s += min(gcur[b], CAP);
    }
    cbase[NB] = s;
  }
}

// Per bucket: LDS histogram over its 512 nodes + LDS scan -> colptr, dinv.
__global__ __launch_bounds__(1024) void fill2a_k(
    const uint2* __restrict__ bpair, const int* __restrict__ gcur,
    const int* __restrict__ cbase, int* __restrict__ colptr,
    float* __restrict__ dinv, int N, int NB) {
  __shared__ int lhist[BN2];
  __shared__ int pref[BN2];
  const int b = blockIdx.x;
  const int tid = threadIdx.x;
  const int nb0 = b << BSH2;
  const int nn = min(BN2, N - nb0);
  if (tid < BN2) lhist[tid] = 0;
  __syncthreads();
  const size_t wbeg = (size_t)b * CAP;
  const int cnt = min(gcur[b], CAP);
  for (int i = tid; i < cnt; i += 1024) {
    int dl = (int)bpair[wbeg + i].y - nb0;
    atomicAdd(&lhist[dl], 1);
  }
  __syncthreads();
  if (tid < BN2) pref[tid] = lhist[tid];
  __syncthreads();
  for (int off = 1; off < BN2; off <<= 1) {
    int v = 0;
    if (tid < BN2 && tid >= off) v = pref[tid - off];
    __syncthreads();
    if (tid < BN2) pref[tid] += v;
    __syncthreads();
  }
  if (tid < nn) {
    const int excl = pref[tid] - lhist[tid];
    colptr[nb0 + tid] = cbase[b] + excl;
    dinv[nb0 + tid] = rsqrtf(1.0f + (float)lhist[tid]);
  }
  if (b == NB - 1 && tid == 0) colptr[N] = cbase[NB];
}

// Per bucket: scatter edges to exact CSR slots, packing src<<15 | fp16(norm).
// norm = dinv[r]*dinv[c] in [~0.015, 0.5] -> always fp16-normal, sign 0,
// so the 15 low bits of the fp16 encode it exactly; src < 131072 fits 17b.
__global__ __launch_bounds__(1024) void fill2b_k(
    const uint2* __restrict__ bpair, const int* __restrict__ gcur,
    const int* __restrict__ colptr, const float* __restrict__ dinv,
    unsigned* __restrict__ epk, int N, int NB) {
  __shared__ int lcur[BN2];
  __shared__ float ldv[BN2];
  const int b = blockIdx.x;
  const int tid = threadIdx.x;
  const int nb0 = b << BSH2;
  const int nn = min(BN2, N - nb0);
  if (tid < nn) {
    lcur[tid] = colptr[nb0 + tid];
    ldv[tid] = dinv[nb0 + tid];
  }
  __syncthreads();
  const size_t wbeg = (size_t)b * CAP;
  const int cnt = min(gcur[b], CAP);
  for (int i = tid; i < cnt; i += 1024) {
    const uint2 p = bpair[wbeg + i];
    const int dl = (int)p.y - nb0;
    const int slot = atomicAdd(&lcur[dl], 1);
    const float nrm = dinv[p.x] * ldv[dl];
    epk[slot] = (p.x << 15) | (unsigned)__half_as_ushort(__float2half(nrm));
  }
}

// MLP via MFMA: one wave per 16-node tile (layout verified in R3).
// h0/ping written plane-major: [plane=c>>4][node][c&15] bf16.
__global__ __launch_bounds__(256) void mlp_k(
    const void* __restrict__ x, const void* __restrict__ W1,
    const void* __restrict__ b1, const void* __restrict__ W2,
    const void* __restrict__ b2, const int* __restrict__ flags,
    u16* __restrict__ h0, u16* __restrict__ ping, int N) {
  __shared__ __align__(16) short Blds[8192];   // [kstep][lane][j] bf16
  __shared__ float W2s[16 * 64];
  __shared__ float b1s[16];
  __shared__ float b2s[64];
  __shared__ float h1s[WPB][16][17];

  const int tid = threadIdx.x;
  const int f0 = flags[0];

  for (int idx = tid; idx < 8192; idx += 256) {
    int ks = idx >> 9, ln = (idx >> 3) & 63, j = idx & 7;
    int k = ks * 32 + ((ln >> 4) << 3) + j;
    int n = ln & 15;
    float w = loadF(W1, (size_t)k * 16 + n, f0);
    Blds[idx] = (short)f2b(w);
  }
  for (int idx = tid; idx < 1024; idx += 256) W2s[idx] = loadF(W2, idx, f0);
  if (tid < 16) b1s[tid] = loadF(b1, tid, f0);
  else if (tid >= 64 && tid < 128) b2s[tid - 64] = loadF(b2, tid - 64, f0);
  __syncthreads();

  const int lane = tid & 63;
  const int wv = tid >> 6;
  const int tile = (blockIdx.x * WPB + wv) * 16;
  if (tile >= N) return;

  const int m = lane & 15;
  const int quad = lane >> 4;
  const int row = min(tile + m, N - 1);
  const size_t rowbase = (size_t)row * 512 + (quad << 3);

  f32x4 acc = {0.f, 0.f, 0.f, 0.f};
  if (f0) {
    // Prefetch all 16 A-frags: 16 independent 16B loads in flight (was a
    // dependent load->MFMA chain; 40 VGPR -> ~110, still 4 waves/SIMD).
    short8 af[16];
#pragma unroll
    for (int ks = 0; ks < 16; ks++)
      af[ks] = *reinterpret_cast<const short8*>((const u16*)x + rowbase + ks * 32);
#pragma unroll
    for (int ks = 0; ks < 16; ks++) {
      const short8 bf = *reinterpret_cast<const short8*>(&Blds[(ks * 64 + lane) * 8]);
      acc = __builtin_amdgcn_mfma_f32_16x16x32_bf16(af[ks], bf, acc, 0, 0, 0);
    }
  } else {
#pragma unroll
    for (int ks = 0; ks < 16; ks++) {
      short8 a;
      const float* xf = (const float*)x + rowbase + ks * 32;
      const float4 lo = *reinterpret_cast<const float4*>(xf);
      const float4 hi = *reinterpret_cast<const float4*>(xf + 4);
      a[0] = (short)f2b(lo.x); a[1] = (short)f2b(lo.y);
      a[2] = (short)f2b(lo.z); a[3] = (short)f2b(lo.w);
      a[4] = (short)f2b(hi.x); a[5] = (short)f2b(hi.y);
      a[6] = (short)f2b(hi.z); a[7] = (short)f2b(hi.w);
      const short8 bf = *reinterpret_cast<const short8*>(&Blds[(ks * 64 + lane) * 8]);
      acc = __builtin_amdgcn_mfma_f32_16x16x32_bf16(a, bf, acc, 0, 0, 0);
    }
  }

#pragma unroll
  for (int r = 0; r < 4; r++)
    h1s[wv][quad * 4 + r][m] = fmaxf(acc[r] + b1s[m], 0.f);

  for (int mm = 0; mm < 16; mm++) {
    const int node = tile + mm;
    if (node >= N) break;
    float hh = b2s[lane];
#pragma unroll
    for (int j = 0; j < 16; j++) hh += h1s[wv][mm][j] * W2s[(j << 6) + lane];
    const u16 u = f2b(hh);
    const size_t o = ((size_t)(lane >> 4) * N + node) * 16 + (lane & 15);
    h0[o] = u;
    ping[o] = u;
  }
}

#define PLANE_FMA(A0, A1, A2, A3, A4, A5, A6, A7, ee, uu)                     \
  {                                                                           \
    const float nn_ = nrm_of(ee);                                             \
    A0 = fmaf(nn_, blo((uu)[0]), A0); A1 = fmaf(nn_, bhi((uu)[0]), A1);       \
    A2 = fmaf(nn_, blo((uu)[1]), A2); A3 = fmaf(nn_, bhi((uu)[1]), A3);       \
    A4 = fmaf(nn_, blo((uu)[2]), A4); A5 = fmaf(nn_, bhi((uu)[2]), A5);       \
    A6 = fmaf(nn_, blo((uu)[3]), A6); A7 = fmaf(nn_, bhi((uu)[3]), A7);       \
  }

// Channel-split gather: gridDim.y = plane (16 channels, 3.2MB contiguous ->
// L2-resident per XCD). Wave = 4 targets x 8 edge-slots x 2 half-row lanes.
// R0-style unroll 4 (slots t,t+8,t+16,t+24 issued together, two acc banks)
// restores 4+4 outstanding loads per lane; nt on epk/h0/out keeps the L2
// clean for the plane.
__global__ __launch_bounds__(256) void gather_k(
    const u16* __restrict__ hcur, const u16* __restrict__ h0,
    const int* __restrict__ colptr, const unsigned* __restrict__ epk,
    const float* __restrict__ dinv, u16* __restrict__ hnext, int N) {
  const int p = blockIdx.y;                     // channel plane 0..3
  const int lane = threadIdx.x & 63;
  const int wv = threadIdx.x >> 6;
  const int grp = lane >> 4;                    // target within wave
  const int l16 = lane & 15;
  const int es = l16 >> 1;                      // edge slot 0..7
  const int ho = (l16 & 1) << 3;                // 8-channel half offset
  const int gw = blockIdx.x * 16 + wv * 4 + grp;
  if (gw >= N) return;
  const u16* __restrict__ hp = hcur + (((size_t)p * N) << 4);
  const int beg = colptr[gw];
  const int end = colptr[gw + 1];

  float a0 = 0.f, a1 = 0.f, a2 = 0.f, a3 = 0.f;
  float a4 = 0.f, a5 = 0.f, a6 = 0.f, a7 = 0.f;
  float c0 = 0.f, c1 = 0.f, c2 = 0.f, c3 = 0.f;
  float c4 = 0.f, c5 = 0.f, c6 = 0.f, c7 = 0.f;
  int t = beg + es;
  for (; t + 24 < end; t += 32) {
    const unsigned e0 = __builtin_nontemporal_load(epk + t);
    const unsigned e1 = __builtin_nontemporal_load(epk + t + 8);
    const unsigned e2 = __builtin_nontemporal_load(epk + t + 16);
    const unsigned e3 = __builtin_nontemporal_load(epk + t + 24);
    const u32x4 u0 = *reinterpret_cast<const u32x4*>(hp + (((size_t)(e0 >> 15)) << 4) + ho);
    const u32x4 u1 = *reinterpret_cast<const u32x4*>(hp + (((size_t)(e1 >> 15)) << 4) + ho);
    const u32x4 u2 = *reinterpret_cast<const u32x4*>(hp + (((size_t)(e2 >> 15)) << 4) + ho);
    const u32x4 u3 = *reinterpret_cast<const u32x4*>(hp + (((size_t)(e3 >> 15)) << 4) + ho);
    PLANE_FMA(a0, a1, a2, a3, a4, a5, a6, a7, e0, u0);
    PLANE_FMA(c0, c1, c2, c3, c4, c5, c6, c7, e1, u1);
    PLANE_FMA(a0, a1, a2, a3, a4, a5, a6, a7, e2, u2);
    PLANE_FMA(c0, c1, c2, c3, c4, c5, c6, c7, e3, u3);
  }
  for (; t + 8 < end; t += 16) {
    const unsigned e0 = __builtin_nontemporal_load(epk + t);
    const unsigned e1 = __builtin_nontemporal_load(epk + t + 8);
    const u32x4 u0 = *reinterpret_cast<const u32x4*>(hp + (((size_t)(e0 >> 15)) << 4) + ho);
    const u32x4 u1 = *reinterpret_cast<const u32x4*>(hp + (((size_t)(e1 >> 15)) << 4) + ho);
    PLANE_FMA(a0, a1, a2, a3, a4, a5, a6, a7, e0, u0);
    PLANE_FMA(c0, c1, c2, c3, c4, c5, c6, c7, e1, u1);
  }
  if (t < end) {
    const unsigned e0 = __builtin_nontemporal_load(epk + t);
    const u32x4 u0 = *reinterpret_cast<const u32x4*>(hp + (((size_t)(e0 >> 15)) << 4) + ho);
    PLANE_FMA(a0, a1, a2, a3, a4, a5, a6, a7, e0, u0);
  }
  a0 += c0; a1 += c1; a2 += c2; a3 += c3;
  a4 += c4; a5 += c5; a6 += c6; a7 += c7;
  // reduce across the 8 edge slots (lane bits 1..3); half/grp preserved
#pragma unroll
  for (int d = 2; d <= 8; d <<= 1) {
    a0 += __shfl_xor(a0, d, 64); a1 += __shfl_xor(a1, d, 64);
    a2 += __shfl_xor(a2, d, 64); a3 += __shfl_xor(a3, d, 64);
    a4 += __shfl_xor(a4, d, 64); a5 += __shfl_xor(a5, d, 64);
    a6 += __shfl_xor(a6, d, 64); a7 += __shfl_xor(a7, d, 64);
  }
  if (es == 0) {
    const size_t base = (((size_t)p * N + gw) << 4) + ho;
    const u32x4 hs = *reinterpret_cast<const u32x4*>(hcur + base);
    const u32x4 hz =
        __builtin_nontemporal_load(reinterpret_cast<const u32x4*>(h0 + base));
    const float di = dinv[gw];
    const float dd = di * di;
    const float r0 = 0.9f * (a0 + dd * blo(hs[0])) + 0.1f * blo(hz[0]);
    const float r1 = 0.9f * (a1 + dd * bhi(hs[0])) + 0.1f * bhi(hz[0]);
    const float r2 = 0.9f * (a2 + dd * blo(hs[1])) + 0.1f * blo(hz[1]);
    const float r3 = 0.9f * (a3 + dd * bhi(hs[1])) + 0.1f * bhi(hz[1]);
    const float r4 = 0.9f * (a4 + dd * blo(hs[2])) + 0.1f * blo(hz[2]);
    const float r5 = 0.9f * (a5 + dd * bhi(hs[2])) + 0.1f * bhi(hz[2]);
    const float r6 = 0.9f * (a6 + dd * blo(hs[3])) + 0.1f * blo(hz[3]);
    const float r7 = 0.9f * (a7 + dd * bhi(hs[3])) + 0.1f * bhi(hz[3]);
    u32x4 pv;
    pv[0] = pk2(r0, r1); pv[1] = pk2(r2, r3);
    pv[2] = pk2(r4, r5); pv[3] = pk2(r6, r7);
    __builtin_nontemporal_store(pv, reinterpret_cast<u32x4*>(hnext + base));
  }
}

__global__ __launch_bounds__(256) void lsm_k(const u16* __restrict__ hin,
                                             void* __restrict__ out,
                                             const int* __restrict__ flags, int N) {
  const int gw = (int)((blockIdx.x * 256u + threadIdx.x) >> 6);
  if (gw >= N) return;
  const int lane = threadIdx.x & 63;
  const size_t oin = ((size_t)(lane >> 4) * N + gw) * 16 + (lane & 15);
  const float v = __bfloat162float(*reinterpret_cast<const __hip_bfloat16*>(&hin[oin]));
  float m = v;
#pragma unroll
  for (int off = 32; off; off >>= 1) m = fmaxf(m, __shfl_xor(m, off, 64));
  float e = __expf(v - m);
  float ssum = e;
#pragma unroll
  for (int off = 32; off; off >>= 1) ssum += __shfl_xor(ssum, off, 64);
  const float r = v - m - __logf(ssum);
  const size_t o = (((size_t)gw) << 6) + lane;
  if (flags[0]) ((__hip_bfloat16*)out)[o] = __float2bfloat16(r);
  else ((float*)out)[o] = r;
}

extern "C" void kernel_launch(void* const* d_in, const int* in_sizes, int n_in,
                              void* d_out, int out_size, void* d_ws, size_t ws_size,
                              hipStream_t stream) {
  (void)n_in; (void)out_size; (void)ws_size;
  const void* x  = d_in[0];
  const void* W1 = d_in[1];
  const void* b1 = d_in[2];
  const void* W2 = d_in[3];
  const void* b2 = d_in[4];
  const int* ei  = (const int*)d_in[5];

  const int N = in_sizes[0] / 512;
  const int E = in_sizes[5] / 2;
  const int NB = (N + BN2 - 1) >> BSH2;    // 196 for N=100k (fits NBMAX=200)

  char* w = (char*)d_ws;
  size_t off = 0;
  auto alloc = [&](size_t bytes) -> void* {
    void* p = w + off;
    off += (bytes + 255) & ~(size_t)255;
    return p;
  };
  // Region A: bpair bucket regions (build) overlaid by h0+ping (propagate).
  const size_t hb = (size_t)N * 64 * 2;
  const size_t bpb = (size_t)NB * CAP * 8;
  char*  regionA = (char*)alloc(2 * hb > bpb ? 2 * hb : bpb);
  u16*   h0     = (u16*)regionA;
  u16*   ping   = (u16*)(regionA + hb);
  uint2* bpair  = (uint2*)regionA;
  unsigned* epk = (unsigned*)alloc((size_t)E * 4);
  int*   colptr = (int*)alloc(((size_t)N + 1) * 4);
  float* dinv   = (float*)alloc((size_t)N * 4);
  int*   gcur   = (int*)alloc((size_t)NB * 4);
  int*   cbase  = (int*)alloc(((size_t)NB + 1) * 4);
  int*   flags  = (int*)alloc(256);
  u16*   pong   = (u16*)d_out;

  hipMemsetAsync(gcur, 0, (size_t)NB * 4, stream);
  detect_k<<<1, 1024, 0, stream>>>(x, ei, flags);
  scat_k<<<SCWG, 256, 0, stream>>>(ei, E, N, NB, gcur, bpair, flags);
  bscan_k<<<1, 64, 0, stream>>>(gcur, NB, cbase);
  fill2a_k<<<NB, 1024, 0, stream>>>(bpair, gcur, cbase, colptr, dinv, N, NB);
  fill2b_k<<<NB, 1024, 0, stream>>>(bpair, gcur, colptr, dinv, epk, N, NB);
  // mlp after fill2b: h0/ping overwrite bpair (lifetime ended).
  mlp_k<<<(N + 63) / 64, 256, 0, stream>>>(x, W1, b1, W2, b2, flags, h0, ping, N);

  const int gpb = (N + 15) >> 4;           // target blocks per plane
  dim3 ggrid(gpb, 4);                      // x fastest -> plane-major order
  for (int it = 0; it < 10; ++it) {
    if ((it & 1) == 0)
      gather_k<<<ggrid, 256, 0, stream>>>(ping, h0, colptr, epk, dinv, pong, N);
    else
      gather_k<<<ggrid, 256, 0, stream>>>(pong, h0, colptr, epk, dinv, ping, N);
  }
  // it9 wrote ping
  lsm_k<<<(N + WPB - 1) / WPB, 256, 0, stream>>>(ping, d_out, flags, N);
}

// Round 4
// 1044.647 us; speedup vs baseline: 1.5423x; 1.4660x over previous
//
#include <hip/hip_runtime.h>
#include <hip/hip_bf16.h>
#include <hip/hip_fp16.h>

// APPNP: h0 = MLP(x); 10x { h = 0.9 * A_hat h + 0.1 * h0 }; log_softmax.
// A_hat = D^-1/2 (A + I) D^-1/2 over col-targets (PyG gcn_norm).
//
// R7 post-mortem: both channel-split variants (R6/R7) regressed vs R0's
// interleaved gather (84us/iter) -> locality-by-plane falsified. R8: exploit
// rank-16 structure instead. h_k = H_k W2 + s_k b2^T with
//   H_{k+1} = 0.9 A H_k + 0.1 H1   (H1 = relu(xW1+b1), 16ch bf16)
//   s_{k+1} = 0.9 A s_k + 0.1     (scalar f32 per node)
// Gathered bytes/edge drop 128B -> 36B; working set 3.6MB = L2-resident.
// W2/b2 applied once at the end, fused with log_softmax in f32.

typedef unsigned short u16;
typedef __attribute__((ext_vector_type(8))) short short8;
typedef __attribute__((ext_vector_type(4))) float f32x4;
typedef __attribute__((ext_vector_type(4))) unsigned u32x4;

#define WPB 4        // waves per 256-thread block
#define BSH2 9       // 512 nodes per bucket
#define BN2 512
#define NBMAX 200
#define CAP 20480    // slots per bucket region (mean 16.3k, +32 sigma)
#define SCWG 392     // scatter WGs (chunk ~8.2k edges)

// ---- helpers -------------------------------------------------------------
__device__ __forceinline__ float loadF(const void* p, size_t i, int bf) {
  if (bf) return __bfloat162float(((const __hip_bfloat16*)p)[i]);
  return ((const float*)p)[i];
}
__device__ __forceinline__ float blo(unsigned u) {
  return __uint_as_float(u << 16);
}
__device__ __forceinline__ float bhi(unsigned u) {
  return __uint_as_float(u & 0xffff0000u);
}
__device__ __forceinline__ u16 f2b(float v) {
  __hip_bfloat16 b = __float2bfloat16(v);
  return *reinterpret_cast<u16*>(&b);
}
__device__ __forceinline__ unsigned pk2(float lo, float hi) {
  return (unsigned)f2b(lo) | ((unsigned)f2b(hi) << 16);
}
__device__ __forceinline__ int clampN(int v, int N) {
  v = v < 0 ? 0 : v;
  return v >= N ? N - 1 : v;
}
__device__ __forceinline__ float nrm_of(unsigned e) {
  return __half2float(__ushort_as_half((unsigned short)(e & 0x7fffu)));
}

// flags[0]: 1 if float tensors bf16; flags[1]: 1 if edge_index int64.
__global__ void detect_k(const void* x, const int* ei, int* flags) {
  __shared__ int red[2];
  const int tid = threadIdx.x;              // 1024 threads
  if (tid < 2) red[tid] = 0;
  __syncthreads();
  const __hip_bfloat16* xb = (const __hip_bfloat16*)x;
  float v = __bfloat162float(xb[tid]);
  int sane = (v == v && fabsf(v) < 64.f) ? 1 : 0;
  int zer = (ei[2 * tid + 1] == 0) ? 1 : 0;
  atomicAdd(&red[0], sane);
  atomicAdd(&red[1], zer);
  __syncthreads();
  if (tid == 0) {
    flags[0] = (red[0] >= 1024 - 32) ? 1 : 0;
    flags[1] = (red[1] >= 1024 - 128) ? 1 : 0;
  }
}

// Two-pass chunked scatter: per WG, (A) LDS-histogram chunk over buckets,
// (B) reserve one contiguous range per bucket, (C) re-read chunk and write
// (src,dst) into the WG-owned run -> full-line writes from one CU.
__global__ __launch_bounds__(256) void scat_k(
    const int* __restrict__ ei, int E, int N, int NB,
    int* __restrict__ gcur, uint2* __restrict__ bpair,
    const int* __restrict__ flags) {
  __shared__ int hist[NBMAX];
  __shared__ int resv[NBMAX];
  const int tid = threadIdx.x;
  const int chunk = (E + SCWG - 1) / SCWG;
  const int e0 = blockIdx.x * chunk;
  const int e1 = min(e0 + chunk, E);
  if (e0 >= E) return;
  const int wide = flags[1];
  for (int i = tid; i < NB; i += 256) hist[i] = 0;
  __syncthreads();
  for (int e = e0 + tid; e < e1; e += 256) {
    int c = wide ? ei[2 * ((long)E + e)] : ei[(long)E + e];
    atomicAdd(&hist[clampN(c, N) >> BSH2], 1);
  }
  __syncthreads();
  for (int b = tid; b < NB; b += 256) {
    int cnt = hist[b];
    resv[b] = cnt ? atomicAdd(&gcur[b], cnt) : 0;
  }
  __syncthreads();
  for (int i = tid; i < NB; i += 256) hist[i] = 0;
  __syncthreads();
  for (int e = e0 + tid; e < e1; e += 256) {
    int r = wide ? ei[2 * (long)e] : ei[e];
    int c = wide ? ei[2 * ((long)E + e)] : ei[(long)E + e];
    r = clampN(r, N); c = clampN(c, N);
    const int b = c >> BSH2;
    const int pos = resv[b] + atomicAdd(&hist[b], 1);
    if (pos < CAP)
      bpair[(size_t)b * CAP + pos] = make_uint2((unsigned)r, (unsigned)c);
  }
}

// Tiny serial scan over bucket totals -> CSR bucket bases.
__global__ void bscan_k(const int* __restrict__ gcur, int NB,
                        int* __restrict__ cbase) {
  if (threadIdx.x == 0) {
    int s = 0;
    for (int b = 0; b < NB; b++) {
      cbase[b] = s;
      s += min(gcur[b], CAP);
    }
    cbase[NB] = s;
  }
}

// Per bucket: LDS histogram over its 512 nodes + LDS scan -> colptr, dinv.
__global__ __launch_bounds__(1024) void fill2a_k(
    const uint2* __restrict__ bpair, const int* __restrict__ gcur,
    const int* __restrict__ cbase, int* __restrict__ colptr,
    float* __restrict__ dinv, int N, int NB) {
  __shared__ int lhist[BN2];
  __shared__ int pref[BN2];
  const int b = blockIdx.x;
  const int tid = threadIdx.x;
  const int nb0 = b << BSH2;
  const int nn = min(BN2, N - nb0);
  if (tid < BN2) lhist[tid] = 0;
  __syncthreads();
  const size_t wbeg = (size_t)b * CAP;
  const int cnt = min(gcur[b], CAP);
  for (int i = tid; i < cnt; i += 1024) {
    int dl = (int)bpair[wbeg + i].y - nb0;
    atomicAdd(&lhist[dl], 1);
  }
  __syncthreads();
  if (tid < BN2) pref[tid] = lhist[tid];
  __syncthreads();
  for (int off = 1; off < BN2; off <<= 1) {
    int v = 0;
    if (tid < BN2 && tid >= off) v = pref[tid - off];
    __syncthreads();
    if (tid < BN2) pref[tid] += v;
    __syncthreads();
  }
  if (tid < nn) {
    const int excl = pref[tid] - lhist[tid];
    colptr[nb0 + tid] = cbase[b] + excl;
    dinv[nb0 + tid] = rsqrtf(1.0f + (float)lhist[tid]);
  }
  if (b == NB - 1 && tid == 0) colptr[N] = cbase[NB];
}

// Per bucket: scatter edges to exact CSR slots, packing src<<15 | fp16(norm).
// norm = dinv[r]*dinv[c] in (~0.014, 1.0] -> always fp16-normal, sign 0,
// so the 15 low bits of the fp16 encode it exactly; src < 131072 fits 17b.
__global__ __launch_bounds__(1024) void fill2b_k(
    const uint2* __restrict__ bpair, const int* __restrict__ gcur,
    const int* __restrict__ colptr, const float* __restrict__ dinv,
    unsigned* __restrict__ epk, int N, int NB) {
  __shared__ int lcur[BN2];
  __shared__ float ldv[BN2];
  const int b = blockIdx.x;
  const int tid = threadIdx.x;
  const int nb0 = b << BSH2;
  const int nn = min(BN2, N - nb0);
  if (tid < nn) {
    lcur[tid] = colptr[nb0 + tid];
    ldv[tid] = dinv[nb0 + tid];
  }
  __syncthreads();
  const size_t wbeg = (size_t)b * CAP;
  const int cnt = min(gcur[b], CAP);
  for (int i = tid; i < cnt; i += 1024) {
    const uint2 p = bpair[wbeg + i];
    const int dl = (int)p.y - nb0;
    const int slot = atomicAdd(&lcur[dl], 1);
    const float nrm = dinv[p.x] * ldv[dl];
    epk[slot] = (p.x << 15) | (unsigned)__half_as_ushort(__float2half(nrm));
  }
}

// MLP stage 1 only: H1 = relu(x@W1 + b1), [N,16] bf16 rows, written to
// h10 (the 0.1*H1 source) and pha (iteration ping buffer); s init = 1.0f.
__global__ __launch_bounds__(256) void mlp_k(
    const void* __restrict__ x, const void* __restrict__ W1,
    const void* __restrict__ b1, const int* __restrict__ flags,
    u16* __restrict__ h10, u16* __restrict__ pha, float* __restrict__ sa,
    int N) {
  __shared__ __align__(16) short Blds[8192];   // [kstep][lane][j] bf16
  __shared__ float b1s[16];
  __shared__ float h1s[WPB][16][17];

  const int tid = threadIdx.x;
  const int f0 = flags[0];

  for (int idx = tid; idx < 8192; idx += 256) {
    int ks = idx >> 9, ln = (idx >> 3) & 63, j = idx & 7;
    int k = ks * 32 + ((ln >> 4) << 3) + j;
    int n = ln & 15;
    float w = loadF(W1, (size_t)k * 16 + n, f0);
    Blds[idx] = (short)f2b(w);
  }
  if (tid < 16) b1s[tid] = loadF(b1, tid, f0);
  __syncthreads();

  const int lane = tid & 63;
  const int wv = tid >> 6;
  const int tile = (blockIdx.x * WPB + wv) * 16;
  if (tile >= N) return;

  const int m = lane & 15;
  const int quad = lane >> 4;
  const int row = min(tile + m, N - 1);
  const size_t rowbase = (size_t)row * 512 + (quad << 3);

  f32x4 acc = {0.f, 0.f, 0.f, 0.f};
  if (f0) {
    // Prefetch all 16 A-frags: 16 independent 16B loads in flight.
    short8 af[16];
#pragma unroll
    for (int ks = 0; ks < 16; ks++)
      af[ks] = *reinterpret_cast<const short8*>((const u16*)x + rowbase + ks * 32);
#pragma unroll
    for (int ks = 0; ks < 16; ks++) {
      const short8 bf = *reinterpret_cast<const short8*>(&Blds[(ks * 64 + lane) * 8]);
      acc = __builtin_amdgcn_mfma_f32_16x16x32_bf16(af[ks], bf, acc, 0, 0, 0);
    }
  } else {
#pragma unroll
    for (int ks = 0; ks < 16; ks++) {
      short8 a;
      const float* xf = (const float*)x + rowbase + ks * 32;
      const float4 lo = *reinterpret_cast<const float4*>(xf);
      const float4 hi = *reinterpret_cast<const float4*>(xf + 4);
      a[0] = (short)f2b(lo.x); a[1] = (short)f2b(lo.y);
      a[2] = (short)f2b(lo.z); a[3] = (short)f2b(lo.w);
      a[4] = (short)f2b(hi.x); a[5] = (short)f2b(hi.y);
      a[6] = (short)f2b(hi.z); a[7] = (short)f2b(hi.w);
      const short8 bf = *reinterpret_cast<const short8*>(&Blds[(ks * 64 + lane) * 8]);
      acc = __builtin_amdgcn_mfma_f32_16x16x32_bf16(a, bf, acc, 0, 0, 0);
    }
  }

#pragma unroll
  for (int r = 0; r < 4; r++)
    h1s[wv][quad * 4 + r][m] = fmaxf(acc[r] + b1s[m], 0.f);
  // same-wave LDS write->read; compiler inserts lgkmcnt wait, no barrier.

  const int node = lane >> 2;                 // 0..15
  const int gnode = tile + node;
  if (gnode < N) {
    const int cp = (lane & 3) << 2;           // channel offset 0,4,8,12
    uint2 pv;
    pv.x = pk2(h1s[wv][node][cp + 0], h1s[wv][node][cp + 1]);
    pv.y = pk2(h1s[wv][node][cp + 2], h1s[wv][node][cp + 3]);
    *reinterpret_cast<uint2*>(h10 + (((size_t)gnode) << 4) + cp) = pv;
    *reinterpret_cast<uint2*>(pha + (((size_t)gnode) << 4) + cp) = pv;
    if ((lane & 3) == 0) sa[gnode] = 1.0f;
  }
}

// Gather over 16-ch H + scalar s. One target per wave: 16 edge-slots x
// 4 lanes (8B = 4ch each). Unroll 2, two acc banks. Working set 3.6MB ->
// L2-resident. Each q-lane-group independently accumulates the full
// scalar sum (redundant but exact; reduce is over es-lanes only).
__global__ __launch_bounds__(256) void gather_k(
    const u16* __restrict__ hcur, const float* __restrict__ scur,
    const u16* __restrict__ h10, const int* __restrict__ colptr,
    const unsigned* __restrict__ epk, const float* __restrict__ dinv,
    u16* __restrict__ hnext, float* __restrict__ snext, int N) {
  const int gw = (int)((blockIdx.x * 256u + threadIdx.x) >> 6);
  if (gw >= N) return;
  const int lane = threadIdx.x & 63;
  const int es = lane >> 2;                   // edge slot 0..15
  const int q = lane & 3;                     // channel quarter
  const int co = q << 2;                      // channel offset
  const int beg = __builtin_amdgcn_readfirstlane(colptr[gw]);
  const int end = __builtin_amdgcn_readfirstlane(colptr[gw + 1]);

  float a0 = 0.f, a1 = 0.f, a2 = 0.f, a3 = 0.f, as = 0.f;
  float c0 = 0.f, c1 = 0.f, c2 = 0.f, c3 = 0.f, cs = 0.f;
  int t = beg + es;
  for (; t + 16 < end; t += 32) {
    const unsigned e0 = __builtin_nontemporal_load(epk + t);
    const unsigned e1 = __builtin_nontemporal_load(epk + t + 16);
    const unsigned i0 = e0 >> 15, i1 = e1 >> 15;
    const uint2 u0 = *reinterpret_cast<const uint2*>(hcur + (((size_t)i0) << 4) + co);
    const uint2 u1 = *reinterpret_cast<const uint2*>(hcur + (((size_t)i1) << 4) + co);
    const float sv0 = scur[i0], sv1 = scur[i1];
    const float n0 = nrm_of(e0), n1 = nrm_of(e1);
    a0 = fmaf(n0, blo(u0.x), a0); a1 = fmaf(n0, bhi(u0.x), a1);
    a2 = fmaf(n0, blo(u0.y), a2); a3 = fmaf(n0, bhi(u0.y), a3);
    as = fmaf(n0, sv0, as);
    c0 = fmaf(n1, blo(u1.x), c0); c1 = fmaf(n1, bhi(u1.x), c1);
    c2 = fmaf(n1, blo(u1.y), c2); c3 = fmaf(n1, bhi(u1.y), c3);
    cs = fmaf(n1, sv1, cs);
  }
  if (t < end) {
    const unsigned e0 = __builtin_nontemporal_load(epk + t);
    const unsigned i0 = e0 >> 15;
    const uint2 u0 = *reinterpret_cast<const uint2*>(hcur + (((size_t)i0) << 4) + co);
    const float sv0 = scur[i0];
    const float n0 = nrm_of(e0);
    a0 = fmaf(n0, blo(u0.x), a0); a1 = fmaf(n0, bhi(u0.x), a1);
    a2 = fmaf(n0, blo(u0.y), a2); a3 = fmaf(n0, bhi(u0.y), a3);
    as = fmaf(n0, sv0, as);
  }
  a0 += c0; a1 += c1; a2 += c2; a3 += c3; as += cs;
  // reduce across 16 edge slots (lane bits 2..5); q preserved
#pragma unroll
  for (int d = 4; d <= 32; d <<= 1) {
    a0 += __shfl_xor(a0, d, 64); a1 += __shfl_xor(a1, d, 64);
    a2 += __shfl_xor(a2, d, 64); a3 += __shfl_xor(a3, d, 64);
    as += __shfl_xor(as, d, 64);
  }
  if (es == 0) {
    const size_t base = (((size_t)gw) << 4) + co;
    const uint2 hs = *reinterpret_cast<const uint2*>(hcur + base);
    const uint2 hz = *reinterpret_cast<const uint2*>(h10 + base);
    const float di = dinv[gw];
    const float dd = di * di;
    const float r0 = 0.9f * (a0 + dd * blo(hs.x)) + 0.1f * blo(hz.x);
    const float r1 = 0.9f * (a1 + dd * bhi(hs.x)) + 0.1f * bhi(hz.x);
    const float r2 = 0.9f * (a2 + dd * blo(hs.y)) + 0.1f * blo(hz.y);
    const float r3 = 0.9f * (a3 + dd * bhi(hs.y)) + 0.1f * bhi(hz.y);
    uint2 pv;
    pv.x = pk2(r0, r1); pv.y = pk2(r2, r3);
    *reinterpret_cast<uint2*>(hnext + base) = pv;
    if (q == 0) snext[gw] = 0.9f * (as + dd * scur[gw]) + 0.1f;
  }
}

// Final: out = log_softmax(ph1 @ W2 + s * b2), one wave per node, f32 math.
__global__ __launch_bounds__(256) void out_k(
    const u16* __restrict__ ph1, const float* __restrict__ s,
    const void* __restrict__ W2, const void* __restrict__ b2,
    void* __restrict__ out, const int* __restrict__ flags, int N) {
  __shared__ float W2s[16 * 64];
  __shared__ float b2s[64];
  const int tid = threadIdx.x;
  const int f0 = flags[0];
  for (int i = tid; i < 1024; i += 256) W2s[i] = loadF(W2, i, f0);
  if (tid < 64) b2s[tid] = loadF(b2, tid, f0);
  __syncthreads();
  const int gw = (int)((blockIdx.x * 256u + tid) >> 6);
  if (gw >= N) return;
  const int lane = tid & 63;
  const u16* row = ph1 + (((size_t)gw) << 4);
  const u32x4 ua = *reinterpret_cast<const u32x4*>(row);       // ch 0..7
  const u32x4 ub = *reinterpret_cast<const u32x4*>(row + 8);   // ch 8..15
  float h[16];
  h[0] = blo(ua[0]);  h[1] = bhi(ua[0]);  h[2] = blo(ua[1]);  h[3] = bhi(ua[1]);
  h[4] = blo(ua[2]);  h[5] = bhi(ua[2]);  h[6] = blo(ua[3]);  h[7] = bhi(ua[3]);
  h[8] = blo(ub[0]);  h[9] = bhi(ub[0]);  h[10] = blo(ub[1]); h[11] = bhi(ub[1]);
  h[12] = blo(ub[2]); h[13] = bhi(ub[2]); h[14] = blo(ub[3]); h[15] = bhi(ub[3]);
  float v = s[gw] * b2s[lane];
#pragma unroll
  for (int j = 0; j < 16; j++) v = fmaf(h[j], W2s[(j << 6) + lane], v);
  float m = v;
#pragma unroll
  for (int off = 32; off; off >>= 1) m = fmaxf(m, __shfl_xor(m, off, 64));
  float e = __expf(v - m);
  float ssum = e;
#pragma unroll
  for (int off = 32; off; off >>= 1) ssum += __shfl_xor(ssum, off, 64);
  const float r = v - m - __logf(ssum);
  const size_t o = (((size_t)gw) << 6) + lane;
  if (f0) ((__hip_bfloat16*)out)[o] = __float2bfloat16(r);
  else ((float*)out)[o] = r;
}

extern "C" void kernel_launch(void* const* d_in, const int* in_sizes, int n_in,
                              void* d_out, int out_size, void* d_ws, size_t ws_size,
                              hipStream_t stream) {
  (void)n_in; (void)out_size; (void)ws_size;
  const void* x  = d_in[0];
  const void* W1 = d_in[1];
  const void* b1 = d_in[2];
  const void* W2 = d_in[3];
  const void* b2 = d_in[4];
  const int* ei  = (const int*)d_in[5];

  const int N = in_sizes[0] / 512;
  const int E = in_sizes[5] / 2;
  const int NB = (N + BN2 - 1) >> BSH2;    // 196 for N=100k (fits NBMAX=200)

  char* w = (char*)d_ws;
  size_t off = 0;
  auto alloc = [&](size_t bytes) -> void* {
    void* p = w + off;
    off += (bytes + 255) & ~(size_t)255;
    return p;
  };
  // Region A: bpair bucket regions (build) overlaid by the propagation
  // buffers (h10, pha, phb: [N][16] bf16; sa, sb: [N] f32).
  const size_t h16b = (size_t)N * 16 * 2;       // 3.2MB
  const size_t sb_  = ((size_t)N * 4 + 255) & ~(size_t)255;
  const size_t propb = 3 * ((h16b + 255) & ~(size_t)255) + 2 * sb_;
  const size_t bpb = (size_t)NB * CAP * 8;
  char*  regionA = (char*)alloc(propb > bpb ? propb : bpb);
  const size_t h16a = (h16b + 255) & ~(size_t)255;
  u16*   h10 = (u16*)regionA;
  u16*   pha = (u16*)(regionA + h16a);
  u16*   phb = (u16*)(regionA + 2 * h16a);
  float* sa  = (float*)(regionA + 3 * h16a);
  float* sb  = (float*)(regionA + 3 * h16a + sb_);
  uint2* bpair  = (uint2*)regionA;
  unsigned* epk = (unsigned*)alloc((size_t)E * 4);
  int*   colptr = (int*)alloc(((size_t)N + 1) * 4);
  float* dinv   = (float*)alloc((size_t)N * 4);
  int*   gcur   = (int*)alloc((size_t)NB * 4);
  int*   cbase  = (int*)alloc(((size_t)NB + 1) * 4);
  int*   flags  = (int*)alloc(256);

  hipMemsetAsync(gcur, 0, (size_t)NB * 4, stream);
  detect_k<<<1, 1024, 0, stream>>>(x, ei, flags);
  scat_k<<<SCWG, 256, 0, stream>>>(ei, E, N, NB, gcur, bpair, flags);
  bscan_k<<<1, 64, 0, stream>>>(gcur, NB, cbase);
  fill2a_k<<<NB, 1024, 0, stream>>>(bpair, gcur, cbase, colptr, dinv, N, NB);
  fill2b_k<<<NB, 1024, 0, stream>>>(bpair, gcur, colptr, dinv, epk, N, NB);
  // mlp after fill2b: prop buffers overwrite bpair (lifetime ended).
  mlp_k<<<(N + 63) / 64, 256, 0, stream>>>(x, W1, b1, flags, h10, pha, sa, N);

  const int gblocks = (N + WPB - 1) / WPB;
  for (int it = 0; it < 10; ++it) {
    if ((it & 1) == 0)
      gather_k<<<gblocks, 256, 0, stream>>>(pha, sa, h10, colptr, epk, dinv,
                                            phb, sb, N);
    else
      gather_k<<<gblocks, 256, 0, stream>>>(phb, sb, h10, colptr, epk, dinv,
                                            pha, sa, N);
  }
  // it9 (odd) wrote pha/sa
  out_k<<<gblocks, 256, 0, stream>>>(pha, sa, W2, b2, d_out, flags, N);
}